// Round 16
// baseline (575.113 us; speedup 1.0000x reference)
//
#include <hip/hip_runtime.h>
#include <hip/hip_bf16.h>
#include <cstdint>
#include <cstddef>

#define HD   256
#define NV   50000
#define NE   80000
#define NNZC 400000
#define FINC 512
#define NCLS 40

using bf16 = __hip_bfloat16;

typedef short bf16x8v __attribute__((ext_vector_type(8)));
typedef float f32x4   __attribute__((ext_vector_type(4)));
typedef unsigned short u16x8 __attribute__((ext_vector_type(8)));

#define NCH_E ((NE + 1023) / 1024)   // 79
#define NCH_V ((NV + 1023) / 1024)   // 49
#define NBM_V ((NV + 127) / 128)     // 391

// ---------- dtype helpers ----------
__device__ __forceinline__ float b2f(unsigned short u) {
    union { unsigned int i; float f; } c; c.i = ((unsigned int)u) << 16; return c.f;
}
__device__ __forceinline__ unsigned short f2b(float f) {
    union { float f; unsigned int i; } c; c.f = f;
    return (unsigned short)((c.i + 0x7FFFu + ((c.i >> 16) & 1u)) >> 16);
}
__device__ __forceinline__ float4 load4f(const bf16* p) {
    ushort4 u = *reinterpret_cast<const ushort4*>(p);
    return make_float4(b2f(u.x), b2f(u.y), b2f(u.z), b2f(u.w));
}
__device__ __forceinline__ void store4(bf16* p, float4 v) {
    ushort4 u; u.x = f2b(v.x); u.y = f2b(v.y); u.z = f2b(v.z); u.w = f2b(v.w);
    *reinterpret_cast<ushort4*>(p) = u;
}

// ---------- async global->LDS, 16B per lane (bf16 B-staging only; r6 lesson) ----------
__device__ __forceinline__ void gl_lds16(const bf16* g, short* l) {
    __builtin_amdgcn_global_load_lds(
        (const __attribute__((address_space(1))) unsigned int*)g,
        (__attribute__((address_space(3))) unsigned int*)l,
        16, 0, 0);
}

// ---------- merged capture-safe fill + weight prep ----------
__global__ __launch_bounds__(256)
void fill_prep_k(unsigned int* __restrict__ fillp, long long filln,
                 const float* __restrict__ lin_w, const float* __restrict__ w1,
                 const float* __restrict__ w2, const float* __restrict__ w3,
                 const float* __restrict__ cw1, const float* __restrict__ cw2,
                 const float* __restrict__ b2,
                 unsigned short* __restrict__ lin_wt, unsigned short* __restrict__ w1_nb,
                 unsigned short* __restrict__ w2a_nb, unsigned short* __restrict__ w2b_nb,
                 unsigned short* __restrict__ w3t, unsigned short* __restrict__ cw1t,
                 unsigned short* __restrict__ cw2t, float* __restrict__ b2w3)
{
    if (blockIdx.x < 128) {
        long long i = (long long)blockIdx.x * 256 + threadIdx.x;
        for (; i < filln; i += 128 * 256) fillp[i] = 0u;
        return;
    }
    int idx = (blockIdx.x - 128) * 256 + threadIdx.x;
    if (idx < 131072) { int n = idx >> 9, k = idx & 511; lin_wt[idx] = f2b(lin_w[k * 256 + n]); return; }
    idx -= 131072;
    if (idx < 65536) { w1_nb[idx] = f2b(w1[idx]); return; }
    idx -= 65536;
    if (idx < 65536) { w2a_nb[idx] = f2b(w2[idx]); return; }
    idx -= 65536;
    if (idx < 65536) { w2b_nb[idx] = f2b(w2[65536 + idx]); return; }
    idx -= 65536;
    if (idx < 65536) { int n = idx >> 8, k = idx & 255; w3t[idx] = f2b(w3[k * 256 + n]); return; }
    idx -= 65536;
    if (idx < 65536) { int n = idx >> 8, k = idx & 255; cw1t[idx] = f2b(cw1[k * 256 + n]); return; }
    idx -= 65536;
    if (idx < 12288) { int n = idx >> 8, k = idx & 255; cw2t[idx] = f2b((n < NCLS) ? cw2[k * NCLS + n] : 0.f); return; }
    idx -= 12288;
    if (idx < 256) {
        float s = 0.f;
        for (int k = 0; k < 256; ++k) s += b2[k] * w3[k * 256 + idx];
        b2w3[idx] = s;
    }
}

// ---------- combined histogram ----------
__global__ __launch_bounds__(256)
void hist_k(const int* __restrict__ vertex, const int* __restrict__ edges,
            int* __restrict__ cnt_v, int* __restrict__ cnt_e, int nnz)
{
    int i = blockIdx.x * 256 + threadIdx.x;
    if (i < nnz) {
        atomicAdd(&cnt_v[vertex[i]], 1);
        atomicAdd(&cnt_e[edges[i]], 1);
    }
}

// ---------- merged 3-phase scan ----------
__global__ __launch_bounds__(256)
void scan_part2_k(const int* __restrict__ cnt_e, int* __restrict__ off_e, int* __restrict__ part_e,
                  const int* __restrict__ cnt_v, int* __restrict__ off_v, int* __restrict__ part_v)
{
    const int* cnt; int* off; int* part; int n;
    if (blockIdx.y == 0) { cnt = cnt_e; off = off_e; part = part_e; n = NE; }
    else                 { cnt = cnt_v; off = off_v; part = part_v; n = NV; }
    int base = blockIdx.x * 1024;
    if (base >= n) return;
    __shared__ int s[256];
    int idx = base + threadIdx.x * 4;
    int v[4], sum = 0;
    #pragma unroll
    for (int j = 0; j < 4; ++j) { v[j] = (idx + j < n) ? cnt[idx + j] : 0; sum += v[j]; }
    s[threadIdx.x] = sum;
    __syncthreads();
    #pragma unroll
    for (int d = 1; d < 256; d <<= 1) {
        int t = (threadIdx.x >= d) ? s[threadIdx.x - d] : 0;
        __syncthreads();
        s[threadIdx.x] += t;
        __syncthreads();
    }
    int excl = s[threadIdx.x] - sum;
    #pragma unroll
    for (int j = 0; j < 4; ++j) {
        if (idx + j < n) off[idx + j] = excl;
        excl += v[j];
    }
    if (threadIdx.x == 255) part[blockIdx.x] = s[255];
}

__global__ __launch_bounds__(256)
void scan_top2_k(int* __restrict__ part_e, int* __restrict__ end_e,
                 int* __restrict__ part_v, int* __restrict__ end_v)
{
    int* part; int* endp; int nch;
    if (blockIdx.x == 0) { part = part_e; endp = end_e; nch = NCH_E; }
    else                 { part = part_v; endp = end_v; nch = NCH_V; }
    __shared__ int s[256];
    int v = (threadIdx.x < nch) ? part[threadIdx.x] : 0;
    s[threadIdx.x] = v;
    __syncthreads();
    #pragma unroll
    for (int d = 1; d < 256; d <<= 1) {
        int t = (threadIdx.x >= d) ? s[threadIdx.x - d] : 0;
        __syncthreads();
        s[threadIdx.x] += t;
        __syncthreads();
    }
    if (threadIdx.x < nch) part[threadIdx.x] = s[threadIdx.x] - v;
    if (threadIdx.x == 255) *endp = s[255];
}

__global__ __launch_bounds__(256)
void scan_addcur2_k(int* __restrict__ off_e, const int* __restrict__ part_e, int* __restrict__ cur_e,
                    int* __restrict__ off_v, const int* __restrict__ part_v, int* __restrict__ cur_v)
{
    int n; int* off; const int* part; int* cur;
    if (blockIdx.y == 0) { n = NE; off = off_e; part = part_e; cur = cur_e; }
    else                 { n = NV; off = off_v; part = part_v; cur = cur_v; }
    int i = blockIdx.x * 256 + threadIdx.x;
    if (i < n) { int o = off[i] + part[i >> 10]; off[i] = o; cur[i] = o; }
}

// ---------- CSR adjacency fill ----------
__global__ __launch_bounds__(256)
void csr_fill_k(const int* __restrict__ vertex, const int* __restrict__ edges,
                int* __restrict__ cur_e, int* __restrict__ cur_v,
                int* __restrict__ adj_e, int* __restrict__ adj_v, int nnz)
{
    int i = blockIdx.x * 256 + threadIdx.x;
    if (i >= nnz) return;
    int v = vertex[i], e = edges[i];
    adj_e[atomicAdd(&cur_e[e], 1)] = v;
    adj_v[atomicAdd(&cur_v[v], 1)] = e;
}

// ---------- dege2[v] = sum_{e in adj_v[v]} cnt_e[e] ----------
__global__ __launch_bounds__(256)
void dege2_k(const int* __restrict__ cnt_e, const int* __restrict__ adj_v,
             const int* __restrict__ off_v, int* __restrict__ dege2, int n)
{
    int v = blockIdx.x * 256 + threadIdx.x;
    if (v >= n) return;
    int s = 0;
    for (int j = off_v[v]; j < off_v[v + 1]; ++j) s += cnt_e[adj_v[j]];
    dege2[v] = s;
}

// ---------- b1w23[n] = sum_k b1[k] * W23b[k][n] ----------
__global__ __launch_bounds__(256)
void b1w23_k(const float* __restrict__ b1, const unsigned short* __restrict__ W23bt,
             float* __restrict__ o)
{
    int n = threadIdx.x;
    float s = 0.f;
    for (int k = 0; k < 256; ++k) s += b1[k] * b2f(W23bt[n * 256 + k]);
    o[n] = s;
}

// ---------- MFMA bf16 GEMM r16: B-in-LDS-once + A-direct-to-registers ----------
// Per 256-K pass: stage 128x256 B-panel into 64KB LDS (gl_lds16 + swizzle, 2
// barriers), then a BARRIER-FREE unrolled K-loop: A fragments loaded straight
// from global to VGPRs (cls_mfma pattern), B from LDS. Waves slip freely ->
// per-wave ILP hides latency (fixes the m97-class barrier-drain stall that made
// r13-r15 neutral). Operand values and rounding identical to r9 core.
// EPI 0/1: row-major (+bias)(+relu). EPI 3: row-major multi-split.
// EPI 5: PERM split store. EPI 4: perm S/z0 hoisted at kernel start.
template<int EPI, bool AF32>
__global__ __launch_bounds__(256)
void mgemm_k(const void* __restrict__ Agv, const bf16* __restrict__ Bt,
             const float* __restrict__ bias, const float* __restrict__ bias2,
             const int* __restrict__ deg, const int* __restrict__ dege2,
             const bf16* __restrict__ Sb, const bf16* __restrict__ z0b,
             const float* __restrict__ b2w3v, const float* __restrict__ b1w23v,
             bf16* __restrict__ Cg, bf16* __restrict__ Cg2, bf16* __restrict__ Cg3,
             int M, int K, int Nc)
{
    const int nbn = Nc >> 7;
    const int nbm = (M + 127) >> 7;
    const int p   = blockIdx.x;
    const int xcd = p & 7;
    const int q   = p >> 3;
    const int cblk = q % nbn;
    const int rblk = q / nbn;
    const int rb   = rblk * 8 + xcd;
    if (rb >= nbm) return;                 // block-uniform exit (before any barrier)
    const int bn = cblk * 128;
    const int bm = rb * 128;

    __shared__ __align__(16) short Bs[128 * 256];   // 64 KB B-panel (256-K pass)

    const int t  = threadIdx.x;
    const int wv = t >> 6, l = t & 63;
    const int wr = wv >> 1, wc = wv & 1;
    const int l15 = l & 15;

    // ---- EPI4: S/z0 perm loads + bias loads issued EARLY ----
    u16x8 sv8[8], zv8[8];
    float bv[4], bw[4], bb1[4];
    if (EPI == 4) {
        const unsigned short* Sp = (const unsigned short*)Sb + ((size_t)(rb * 2 + cblk) * 256 + t) * 64;
        const unsigned short* Zp = (const unsigned short*)z0b + ((size_t)(rb * 2 + cblk) * 256 + t) * 64;
        #pragma unroll
        for (int j = 0; j < 8; ++j) {
            sv8[j] = *reinterpret_cast<const u16x8*>(Sp + j * 8);
            zv8[j] = *reinterpret_cast<const u16x8*>(Zp + j * 8);
        }
        #pragma unroll
        for (int n = 0; n < 4; ++n) {
            int col = bn + wc * 64 + n * 16 + l15;
            bv[n]  = bias[col];
            bw[n]  = b2w3v[col];
            bb1[n] = b1w23v[col];
        }
    }

    f32x4 acc[4][4];
    #pragma unroll
    for (int m = 0; m < 4; ++m)
        #pragma unroll
        for (int n = 0; n < 4; ++n)
            acc[m][n] = (f32x4){0.f, 0.f, 0.f, 0.f};

    const int brow8   = l >> 3;                       // row within 8-row chunk
    const int bcol_sw = (((l & 7) ^ (l >> 3)) * 8);   // pre-swizzled source col
    const int ko8     = (l >> 4) * 8;                 // lane k sub-offset (elems)

    // A row addresses (clamped) -- shared by all chunks
    size_t arow[4];
    #pragma unroll
    for (int m = 0; m < 4; ++m) {
        int ga = bm + wr * 64 + m * 16 + l15; if (ga >= M) ga = M - 1;
        arow[m] = (size_t)ga * K;
    }

    for (int kh = 0; kh < K; kh += 256) {
        if (kh > 0) __syncthreads();                  // protect Bs overwrite
        // ---- stage B panel: 128 rows(cols) x 256 k = 64 KB, 16 gl_lds/thread ----
        #pragma unroll
        for (int s = 0; s < 4; ++s) {
            #pragma unroll
            for (int i = 0; i < 4; ++i) {
                int c = wv * 4 + i;
                int row = c * 8 + brow8;
                gl_lds16(Bt + (size_t)(bn + row) * K + kh + s * 64 + bcol_sw,
                         Bs + s * 8192 + c * 512);
            }
        }
        __syncthreads();                              // B panel visible

        // ---- barrier-free K compute: 8 chunks of 32 ----
        #pragma unroll
        for (int c32 = 0; c32 < 8; ++c32) {
            int k_abs = kh + c32 * 32 + ko8;
            bf16x8v a[4], b[4];
            if constexpr (AF32) {
                const float* Af = (const float*)Agv;
                #pragma unroll
                for (int m = 0; m < 4; ++m) {
                    const float* src = Af + arow[m] + k_abs;
                    f32x4 u = *reinterpret_cast<const f32x4*>(src);
                    f32x4 v = *reinterpret_cast<const f32x4*>(src + 4);
                    bf16x8v o;
                    o[0] = (short)f2b(u[0]); o[1] = (short)f2b(u[1]);
                    o[2] = (short)f2b(u[2]); o[3] = (short)f2b(u[3]);
                    o[4] = (short)f2b(v[0]); o[5] = (short)f2b(v[1]);
                    o[6] = (short)f2b(v[2]); o[7] = (short)f2b(v[3]);
                    a[m] = o;
                }
            } else {
                const bf16* Ab = (const bf16*)Agv;
                #pragma unroll
                for (int m = 0; m < 4; ++m)
                    a[m] = *reinterpret_cast<const bf16x8v*>(Ab + arow[m] + k_abs);
            }
            const int kb = (c32 & 1) * 64 + (l >> 4) * 16;   // byte offset in 64-k chunk
            const int sB = c32 >> 1;
            #pragma unroll
            for (int n = 0; n < 4; ++n) {
                int r = wc * 64 + n * 16 + l15;
                b[n] = *reinterpret_cast<const bf16x8v*>(
                           (const char*)Bs + sB * 16384 + r * 128 + (kb ^ ((r & 7) << 4)));
            }
            #pragma unroll
            for (int m = 0; m < 4; ++m)
                #pragma unroll
                for (int n = 0; n < 4; ++n)
                    acc[m][n] = __builtin_amdgcn_mfma_f32_16x16x32_bf16(a[m], b[n], acc[m][n], 0, 0, 0);
        }
    }

    if (EPI == 5) {
        int oi = bn >> 8;
        bf16* CC = (oi == 0) ? Cg : Cg2;
        int c2 = (bn >> 7) & 1;
        unsigned short* P = (unsigned short*)CC + ((size_t)(rb * 2 + c2) * 256 + t) * 64;
        #pragma unroll
        for (int m = 0; m < 4; ++m) {
            u16x8 o0, o1;
            #pragma unroll
            for (int n = 0; n < 2; ++n)
                #pragma unroll
                for (int i = 0; i < 4; ++i) {
                    o0[n * 4 + i] = f2b(acc[m][n][i]);
                    o1[n * 4 + i] = f2b(acc[m][n + 2][i]);
                }
            *reinterpret_cast<u16x8*>(P + m * 16)     = o0;
            *reinterpret_cast<u16x8*>(P + m * 16 + 8) = o1;
        }
    } else if (EPI == 4) {
        #pragma unroll
        for (int m = 0; m < 4; ++m) {
            #pragma unroll
            for (int i = 0; i < 4; ++i) {
                int row = bm + wr * 64 + m * 16 + (l >> 4) * 4 + i;
                if (row >= M) continue;
                float d   = (float)deg[row];
                float de2 = (float)dege2[row];
                size_t base = (size_t)row * Nc + bn + wc * 64 + l15;
                #pragma unroll
                for (int n = 0; n < 4; ++n) {
                    int e = m * 16 + n * 4 + i;
                    float sv = b2f(sv8[e >> 3][e & 7]);
                    float zv = b2f(zv8[e >> 3][e & 7]);
                    float v = 0.5f * (d * (sv + bw[n]) + acc[m][n][i] + de2 * bb1[n])
                              + 0.5f * zv + bv[n];
                    v = fmaxf(v, 0.f);
                    reinterpret_cast<unsigned short*>(Cg)[base + (size_t)n * 16] = f2b(v);
                }
            }
        }
    } else if (EPI == 3) {
        int oi = bn >> 8;
        bf16* CC = (oi == 0) ? Cg : (oi == 1) ? Cg2 : Cg3;
        const float* bb = (oi == 0) ? bias : (oi == 1) ? bias2 : nullptr;
        int cb = bn & 255;
        float bvv[4];
        #pragma unroll
        for (int n = 0; n < 4; ++n)
            bvv[n] = bb ? bb[cb + wc * 64 + n * 16 + l15] : 0.f;
        #pragma unroll
        for (int m = 0; m < 4; ++m) {
            #pragma unroll
            for (int i = 0; i < 4; ++i) {
                int row = bm + wr * 64 + m * 16 + (l >> 4) * 4 + i;
                if (row >= M) continue;
                size_t base = (size_t)row * 256 + cb + wc * 64 + l15;
                #pragma unroll
                for (int n = 0; n < 4; ++n)
                    reinterpret_cast<unsigned short*>(CC)[base + n * 16] = f2b(acc[m][n][i] + bvv[n]);
            }
        }
    } else {
        float bvv[4];
        #pragma unroll
        for (int n = 0; n < 4; ++n)
            bvv[n] = bias ? bias[bn + wc * 64 + n * 16 + l15] : 0.f;
        #pragma unroll
        for (int m = 0; m < 4; ++m) {
            #pragma unroll
            for (int i = 0; i < 4; ++i) {
                int row = bm + wr * 64 + m * 16 + (l >> 4) * 4 + i;
                if (row >= M) continue;
                size_t base = (size_t)row * Nc + bn + wc * 64 + l15;
                #pragma unroll
                for (int n = 0; n < 4; ++n) {
                    float v = acc[m][n][i] + bvv[n];
                    if (EPI == 1) v = fmaxf(v, 0.f);
                    reinterpret_cast<unsigned short*>(Cg)[base + n * 16] = f2b(v);
                }
            }
        }
    }
}

// ---------- gather segment-sum ----------
__global__ __launch_bounds__(256)
void gather_sum_k(const bf16* __restrict__ src, const int* __restrict__ adj,
                  const int* __restrict__ off, bf16* __restrict__ dst, int nseg)
{
    int seg = blockIdx.x * 4 + (threadIdx.x >> 6);
    if (seg >= nseg) return;
    int lane = threadIdx.x & 63;
    int s0 = off[seg], s1 = off[seg + 1];
    float4 acc = make_float4(0.f, 0.f, 0.f, 0.f);
    int j = s0;
    for (; j + 4 <= s1; j += 4) {
        int r0 = adj[j], r1 = adj[j + 1], r2 = adj[j + 2], r3 = adj[j + 3];
        float4 v0 = load4f(src + (size_t)r0 * HD + lane * 4);
        float4 v1 = load4f(src + (size_t)r1 * HD + lane * 4);
        float4 v2 = load4f(src + (size_t)r2 * HD + lane * 4);
        float4 v3 = load4f(src + (size_t)r3 * HD + lane * 4);
        acc.x += (v0.x + v1.x) + (v2.x + v3.x);
        acc.y += (v0.y + v1.y) + (v2.y + v3.y);
        acc.z += (v0.z + v1.z) + (v2.z + v3.z);
        acc.w += (v0.w + v1.w) + (v2.w + v3.w);
    }
    for (; j < s1; ++j) {
        float4 v = load4f(src + (size_t)adj[j] * HD + lane * 4);
        acc.x += v.x; acc.y += v.y; acc.z += v.z; acc.w += v.w;
    }
    store4(dst + (size_t)seg * HD + lane * 4, acc);
}

// ---------- MFMA classifier ----------
__global__ __launch_bounds__(256)
void cls_mfma_k(const bf16* __restrict__ Hm, const bf16* __restrict__ Wt,
                const float* __restrict__ bias, float* __restrict__ out, int M)
{
    const int wv = threadIdx.x >> 6, l = threadIdx.x & 63;
    const int l15 = l & 15;
    const int r0 = blockIdx.x * 64 + wv * 16;
    f32x4 acc[3];
    #pragma unroll
    for (int n = 0; n < 3; ++n) acc[n] = (f32x4){0.f, 0.f, 0.f, 0.f};

    int arow = r0 + l15; if (arow >= M) arow = M - 1;
    const int ko = (l >> 4) * 8;
    for (int kk = 0; kk < HD; kk += 32) {
        bf16x8v a = *reinterpret_cast<const bf16x8v*>(Hm + (size_t)arow * HD + kk + ko);
        #pragma unroll
        for (int n = 0; n < 3; ++n) {
            bf16x8v b = *reinterpret_cast<const bf16x8v*>(Wt + (size_t)(n * 16 + l15) * HD + kk + ko);
            acc[n] = __builtin_amdgcn_mfma_f32_16x16x32_bf16(a, b, acc[n], 0, 0, 0);
        }
    }
    #pragma unroll
    for (int n = 0; n < 3; ++n) {
        int col = n * 16 + l15;
        if (col >= NCLS) continue;
        float bv = bias[col];
        #pragma unroll
        for (int i = 0; i < 4; ++i) {
            int row = r0 + (l >> 4) * 4 + i;
            if (row < M) out[(size_t)row * NCLS + col] = acc[n][i] + bv;
        }
    }
}

static inline int xcd_grid(int M, int Nc)
{
    int nbm = (M + 127) >> 7;
    int nbn = Nc >> 7;
    return nbn * (((nbm + 7) / 8) * 8);
}

extern "C" void kernel_launch(void* const* d_in, const int* in_sizes, int n_in,
                              void* d_out, int out_size, void* d_ws, size_t ws_size,
                              hipStream_t stream)
{
    const float* x_in   = (const float*)d_in[0];
    const int*   vertex = (const int*)d_in[1];
    const int*   edges  = (const int*)d_in[2];
    const float* lin_w  = (const float*)d_in[3];
    const float* lin_b  = (const float*)d_in[4];
    const float* w1     = (const float*)d_in[5];
    const float* b1     = (const float*)d_in[6];
    const float* w2     = (const float*)d_in[7];
    const float* b2     = (const float*)d_in[8];
    const float* w3     = (const float*)d_in[9];
    const float* b3     = (const float*)d_in[10];
    const float* cw1    = (const float*)d_in[11];
    const float* cb1    = (const float*)d_in[12];
    const float* cw2    = (const float*)d_in[13];
    const float* cb2    = (const float*)d_in[14];
    float* out = (float*)d_out;
    (void)in_sizes; (void)n_in; (void)out_size; (void)ws_size;

    char* ws = (char*)d_ws;
    const size_t nvhd = (size_t)NV * HD, nehd = (size_t)NE * HD;
    const size_t permsz = (size_t)(NBM_V + 1) * 2 * 256 * 64;
    size_t off = 0;
    auto alloc = [&](size_t bytes) { char* p = ws + off; off += (bytes + 255) & ~(size_t)255; return p; };
    bf16* x0 = (bf16*)alloc(nvhd * 2);
    bf16* xA = (bf16*)alloc(nvhd * 2);
    bf16* E1 = (bf16*)alloc(nehd * 2);
    bf16* E2 = (bf16*)alloc(nehd * 2);
    bf16* S  = (bf16*)alloc(permsz * 2);        // PERM layout
    bf16* z0 = (bf16*)alloc(permsz * 2);        // PERM layout
    unsigned short* W23at  = (unsigned short*)alloc(2 * 256 * 256 * 2);  // [W23at ; w3t]
    unsigned short* w3t    = W23at + 65536;
    unsigned short* W23bt  = (unsigned short*)alloc(256 * 256 * 2);
    unsigned short* W123bt = (unsigned short*)alloc(256 * 256 * 2);
    unsigned short* w2ab   = (unsigned short*)alloc(512 * 256 * 2);
    unsigned short* w2a_nb = w2ab;
    unsigned short* w2b_nb = w2ab + 256 * 256;
    unsigned short* w1_nb  = (unsigned short*)alloc(256 * 256 * 2);
    unsigned short* lin_wt = (unsigned short*)alloc(256 * 512 * 2);
    unsigned short* cw1t   = (unsigned short*)alloc(256 * 256 * 2);
    unsigned short* cw2t   = (unsigned short*)alloc(48 * 256 * 2);
    float* b2w3  = (float*)alloc(256 * 4);
    float* b1w23 = (float*)alloc(256 * 4);
    int* cnt_e = (int*)alloc(NE * 4);            // cnt_v must follow (single fill)
    int* cnt_v = (int*)alloc(NV * 4);
    int* dege2 = (int*)alloc(NV * 4);
    int* off_e = (int*)alloc((NE + 1) * 4);
    int* off_v = (int*)alloc((NV + 1) * 4);
    int* cur_e = (int*)alloc(NE * 4);
    int* cur_v = (int*)alloc(NV * 4);
    int* part_e = (int*)alloc(256 * 4);
    int* part_v = (int*)alloc(256 * 4);
    int* adj_e = (int*)alloc((size_t)NNZC * 4);
    int* adj_v = (int*)alloc((size_t)NNZC * 4);

    dim3 blk(256);

    // ---- CSR build + weight prep ----
    fill_prep_k<<<128 + 1841, blk, 0, stream>>>((unsigned int*)cnt_e, NE + NV,
        lin_w, w1, w2, w3, cw1, cw2, b2,
        lin_wt, w1_nb, w2a_nb, w2b_nb, w3t, cw1t, cw2t, b2w3);
    hist_k<<<(NNZC + 255) / 256, blk, 0, stream>>>(vertex, edges, cnt_v, cnt_e, NNZC);
    scan_part2_k<<<dim3(NCH_E, 2), blk, 0, stream>>>(cnt_e, off_e, part_e, cnt_v, off_v, part_v);
    scan_top2_k<<<2, blk, 0, stream>>>(part_e, off_e + NE, part_v, off_v + NV);
    scan_addcur2_k<<<dim3((NE + 255) / 256, 2), blk, 0, stream>>>(off_e, part_e, cur_e,
                                                                  off_v, part_v, cur_v);
    csr_fill_k<<<(NNZC + 255) / 256, blk, 0, stream>>>(vertex, edges, cur_e, cur_v, adj_e, adj_v, NNZC);
    dege2_k<<<(NV + 255) / 256, blk, 0, stream>>>(cnt_e, adj_v, off_v, dege2, NV);

    // ---- weight compositions ----
    mgemm_k<3, false><<<xcd_grid(256, 512), blk, 0, stream>>>((const bf16*)w3t, (const bf16*)w2ab,
        nullptr, nullptr, nullptr, nullptr, nullptr, nullptr, nullptr, nullptr,
        (bf16*)W23at, (bf16*)W23bt, nullptr, 256, 256, 512);
    mgemm_k<0, false><<<xcd_grid(256, 256), blk, 0, stream>>>((const bf16*)W23bt, (const bf16*)w1_nb,
        nullptr, nullptr, nullptr, nullptr, nullptr, nullptr, nullptr, nullptr,
        (bf16*)W123bt, nullptr, nullptr, 256, 256, 256);
    b1w23_k<<<1, blk, 0, stream>>>(b1, W23bt, b1w23);

    // ---- input projection (AF32, A direct-from-global) ----
    mgemm_k<1, true><<<xcd_grid(NV, 256), blk, 0, stream>>>(x_in, (const bf16*)lin_wt,
        lin_b, nullptr, nullptr, nullptr, nullptr, nullptr, nullptr, nullptr,
        x0, nullptr, nullptr, NV, FINC, HD);

    const bf16* cur = x0;
    for (int layer = 0; layer < 2; ++layer) {
        if (layer == 0) {
            // [S | z0] = x0 @ [W23at ; w3t]   (dual GEMM, PERM stores)
            mgemm_k<5, false><<<xcd_grid(NV, 512), blk, 0, stream>>>(cur, (const bf16*)W23at,
                nullptr, nullptr, nullptr, nullptr, nullptr, nullptr, nullptr, nullptr,
                S, z0, nullptr, NV, HD, 512);
        } else {
            // S = cur @ W23at   (PERM store)
            mgemm_k<5, false><<<xcd_grid(NV, 256), blk, 0, stream>>>(cur, (const bf16*)W23at,
                nullptr, nullptr, nullptr, nullptr, nullptr, nullptr, nullptr, nullptr,
                S, nullptr, nullptr, NV, HD, HD);
        }
        // E2 = gather_e(cur); E1 = gather_v(E2)
        gather_sum_k<<<(NE + 3) / 4, blk, 0, stream>>>(cur, adj_e, off_e, E2, NE);
        gather_sum_k<<<(NV + 3) / 4, blk, 0, stream>>>(E2, adj_v, off_v, E1, NV);
        // xA = relu(0.5*(deg*(S+b2w3) + g2cur@W123b + dege2*b1w23) + 0.5*z0 + b3)
        mgemm_k<4, false><<<xcd_grid(NV, 256), blk, 0, stream>>>(E1, (const bf16*)W123bt,
            b3, nullptr, cnt_v, dege2, S, z0, b2w3, b1w23,
            xA, nullptr, nullptr, NV, HD, HD);
        cur = xA;
    }

    // ---- classifier ----
    mgemm_k<1, false><<<xcd_grid(NV, 256), blk, 0, stream>>>(xA, (const bf16*)cw1t,
        cb1, nullptr, nullptr, nullptr, nullptr, nullptr, nullptr, nullptr,
        E1, nullptr, nullptr, NV, HD, HD);
    cls_mfma_k<<<(NV + 63) / 64, blk, 0, stream>>>(E1, (const bf16*)cw2t, cb2, out, NV);
}

// Round 17
// 472.201 us; speedup vs baseline: 1.2179x; 1.2179x over previous
//
#include <hip/hip_runtime.h>
#include <hip/hip_bf16.h>
#include <cstdint>
#include <cstddef>

#define HD   256
#define NV   50000
#define NE   80000
#define NNZC 400000
#define FINC 512
#define NCLS 40

using bf16 = __hip_bfloat16;

typedef short bf16x8v __attribute__((ext_vector_type(8)));
typedef float f32x4   __attribute__((ext_vector_type(4)));

#define NCH_E ((NE + 1023) / 1024)   // 79
#define NCH_V ((NV + 1023) / 1024)   // 49

// ---------- dtype helpers ----------
__device__ __forceinline__ float b2f(unsigned short u) {
    union { unsigned int i; float f; } c; c.i = ((unsigned int)u) << 16; return c.f;
}
__device__ __forceinline__ unsigned short f2b(float f) {
    union { float f; unsigned int i; } c; c.f = f;
    return (unsigned short)((c.i + 0x7FFFu + ((c.i >> 16) & 1u)) >> 16);
}
__device__ __forceinline__ float4 load4f(const bf16* p) {
    ushort4 u = *reinterpret_cast<const ushort4*>(p);
    return make_float4(b2f(u.x), b2f(u.y), b2f(u.z), b2f(u.w));
}
__device__ __forceinline__ void store4(bf16* p, float4 v) {
    ushort4 u; u.x = f2b(v.x); u.y = f2b(v.y); u.z = f2b(v.z); u.w = f2b(v.w);
    *reinterpret_cast<ushort4*>(p) = u;
}

// ---------- async global->LDS, 16B per lane (LDS base wave-uniform, dest LINEAR) ----------
// r6 lesson: bf16 staging only, exact r4/r5 pattern. f32 A staged via regs+ds_write.
// r8: source global address is per-lane -> pre-swizzled source col gives swizzled LDS
// layout with linear dest (rule #21 correct form).
__device__ __forceinline__ void gl_lds16(const bf16* g, short* l) {
    __builtin_amdgcn_global_load_lds(
        (const __attribute__((address_space(1))) unsigned int*)g,
        (__attribute__((address_space(3))) unsigned int*)l,
        16, 0, 0);
}

// ---------- capture-safe zero fill ----------
__global__ __launch_bounds__(256)
void fill0_k(unsigned int* __restrict__ p, long long n)
{
    long long i = (long long)blockIdx.x * 256 + threadIdx.x;
    long long stride = (long long)gridDim.x * 256;
    for (; i < n; i += stride) p[i] = 0u;
}

// ---------- combined histogram ----------
__global__ __launch_bounds__(256)
void hist_k(const int* __restrict__ vertex, const int* __restrict__ edges,
            int* __restrict__ cnt_v, int* __restrict__ cnt_e, int nnz)
{
    int i = blockIdx.x * 256 + threadIdx.x;
    if (i < nnz) {
        atomicAdd(&cnt_v[vertex[i]], 1);
        atomicAdd(&cnt_e[edges[i]], 1);
    }
}

// ---------- merged 3-phase scan (y=0: edges, y=1: vertices) ----------
__global__ __launch_bounds__(256)
void scan_part2_k(const int* __restrict__ cnt_e, int* __restrict__ off_e, int* __restrict__ part_e,
                  const int* __restrict__ cnt_v, int* __restrict__ off_v, int* __restrict__ part_v)
{
    const int* cnt; int* off; int* part; int n;
    if (blockIdx.y == 0) { cnt = cnt_e; off = off_e; part = part_e; n = NE; }
    else                 { cnt = cnt_v; off = off_v; part = part_v; n = NV; }
    int base = blockIdx.x * 1024;
    if (base >= n) return;
    __shared__ int s[256];
    int idx = base + threadIdx.x * 4;
    int v[4], sum = 0;
    #pragma unroll
    for (int j = 0; j < 4; ++j) { v[j] = (idx + j < n) ? cnt[idx + j] : 0; sum += v[j]; }
    s[threadIdx.x] = sum;
    __syncthreads();
    #pragma unroll
    for (int d = 1; d < 256; d <<= 1) {
        int t = (threadIdx.x >= d) ? s[threadIdx.x - d] : 0;
        __syncthreads();
        s[threadIdx.x] += t;
        __syncthreads();
    }
    int excl = s[threadIdx.x] - sum;
    #pragma unroll
    for (int j = 0; j < 4; ++j) {
        if (idx + j < n) off[idx + j] = excl;
        excl += v[j];
    }
    if (threadIdx.x == 255) part[blockIdx.x] = s[255];
}

__global__ __launch_bounds__(256)
void scan_top2_k(int* __restrict__ part_e, int* __restrict__ end_e,
                 int* __restrict__ part_v, int* __restrict__ end_v)
{
    int* part; int* endp; int nch;
    if (blockIdx.x == 0) { part = part_e; endp = end_e; nch = NCH_E; }
    else                 { part = part_v; endp = end_v; nch = NCH_V; }
    __shared__ int s[256];
    int v = (threadIdx.x < nch) ? part[threadIdx.x] : 0;
    s[threadIdx.x] = v;
    __syncthreads();
    #pragma unroll
    for (int d = 1; d < 256; d <<= 1) {
        int t = (threadIdx.x >= d) ? s[threadIdx.x - d] : 0;
        __syncthreads();
        s[threadIdx.x] += t;
        __syncthreads();
    }
    if (threadIdx.x < nch) part[threadIdx.x] = s[threadIdx.x] - v;
    if (threadIdx.x == 255) *endp = s[255];
}

// off[i] += part[chunk]; cur[i] = off[i]
__global__ __launch_bounds__(256)
void scan_addcur2_k(int* __restrict__ off_e, const int* __restrict__ part_e, int* __restrict__ cur_e,
                    int* __restrict__ off_v, const int* __restrict__ part_v, int* __restrict__ cur_v)
{
    int n; int* off; const int* part; int* cur;
    if (blockIdx.y == 0) { n = NE; off = off_e; part = part_e; cur = cur_e; }
    else                 { n = NV; off = off_v; part = part_v; cur = cur_v; }
    int i = blockIdx.x * 256 + threadIdx.x;
    if (i < n) { int o = off[i] + part[i >> 10]; off[i] = o; cur[i] = o; }
}

// ---------- CSR adjacency fill ----------
__global__ __launch_bounds__(256)
void csr_fill_k(const int* __restrict__ vertex, const int* __restrict__ edges,
                int* __restrict__ cur_e, int* __restrict__ cur_v,
                int* __restrict__ adj_e, int* __restrict__ adj_v, int nnz)
{
    int i = blockIdx.x * 256 + threadIdx.x;
    if (i >= nnz) return;
    int v = vertex[i], e = edges[i];
    adj_e[atomicAdd(&cur_e[e], 1)] = v;
    adj_v[atomicAdd(&cur_v[v], 1)] = e;
}

// ---------- weight prep (+ b2w3 tail) ----------
__global__ __launch_bounds__(256)
void prep_w_k(const float* __restrict__ lin_w, const float* __restrict__ w1,
              const float* __restrict__ w2, const float* __restrict__ w3,
              const float* __restrict__ cw1, const float* __restrict__ cw2,
              const float* __restrict__ b2,
              unsigned short* __restrict__ lin_wt, unsigned short* __restrict__ w1t,
              unsigned short* __restrict__ w2a_nb, unsigned short* __restrict__ w2b_nb,
              unsigned short* __restrict__ w3t, unsigned short* __restrict__ cw1t,
              unsigned short* __restrict__ cw2t, float* __restrict__ b2w3)
{
    int idx = blockIdx.x * 256 + threadIdx.x;          // < 471296
    if (idx < 131072) { int n = idx >> 9, k = idx & 511; lin_wt[idx] = f2b(lin_w[k * 256 + n]); return; }
    idx -= 131072;
    if (idx < 65536) { int n = idx >> 8, k = idx & 255; w1t[idx] = f2b(w1[k * 256 + n]); return; }
    idx -= 65536;
    if (idx < 65536) { w2a_nb[idx] = f2b(w2[idx]); return; }
    idx -= 65536;
    if (idx < 65536) { w2b_nb[idx] = f2b(w2[65536 + idx]); return; }
    idx -= 65536;
    if (idx < 65536) { int n = idx >> 8, k = idx & 255; w3t[idx] = f2b(w3[k * 256 + n]); return; }
    idx -= 65536;
    if (idx < 65536) { int n = idx >> 8, k = idx & 255; cw1t[idx] = f2b(cw1[k * 256 + n]); return; }
    idx -= 65536;
    if (idx < 12288) { int n = idx >> 8, k = idx & 255; cw2t[idx] = f2b((n < NCLS) ? cw2[k * NCLS + n] : 0.f); return; }
    idx -= 12288;
    if (idx < 256) {
        float s = 0.f;
        for (int k = 0; k < 256; ++k) s += b2[k] * w3[k * 256 + idx];
        b2w3[idx] = s;
    }
}

// ---------- MFMA bf16 GEMM: 128x128 tile, BK=64, 4 waves ----------
// r8 additions:
//  * 1-D XCD-grouped grid: p -> {xcd=p&7, q=p>>3, cblk=q%nbn, rblk=q/nbn, r=rblk*8+xcd}
//    so the nbn col-blocks of one row panel are 8 apart in linear id -> same XCD L2.
//  * LDS st-swizzle: source col ((l&7)^(l>>3))*8 with linear LDS dest; reads XOR
//    byte offset with (row&7)<<4. Breaks the 16-way ds_read_b128 bank conflict.
// EPI 0: C = A@Bt^T (+bias); EPI 1: + relu
// EPI 3: multi split (Nc=256*k, k<=3): col-block oi -> Cg/Cg2/Cg3, each [M][256]
// EPI 4: C = relu(0.5*(deg[row]*(S+b2w3) + acc) + 0.5*z0 + bias)
template<int EPI, bool AF32>
__global__ __launch_bounds__(256)
void mgemm_k(const void* __restrict__ Agv, const bf16* __restrict__ Bt,
             const float* __restrict__ bias, const float* __restrict__ bias2,
             const int* __restrict__ deg,
             const bf16* __restrict__ Sb, const bf16* __restrict__ z0b,
             const float* __restrict__ b2w3v,
             bf16* __restrict__ Cg, bf16* __restrict__ Cg2, bf16* __restrict__ Cg3,
             int M, int K, int Nc)
{
    const int nbn = Nc >> 7;
    const int nbm = (M + 127) >> 7;
    const int p   = blockIdx.x;
    const int xcd = p & 7;
    const int q   = p >> 3;
    const int cblk = q % nbn;
    const int rblk = q / nbn;
    const int rb   = rblk * 8 + xcd;
    if (rb >= nbm) return;                 // block-uniform exit (before any barrier)
    const int bn = cblk * 128;
    const int bm = rb * 128;

    __shared__ __align__(16) short As[128 * 64];
    __shared__ __align__(16) short Bs[128 * 64];

    const int t  = threadIdx.x;
    const int wv = t >> 6, l = t & 63;
    const int wr = wv >> 1, wc = wv & 1;
    const int l15 = l & 15;

    f32x4 acc[4][4];
    #pragma unroll
    for (int m = 0; m < 4; ++m)
        #pragma unroll
        for (int n = 0; n < 4; ++n)
            acc[m][n] = (f32x4){0.f, 0.f, 0.f, 0.f};

    const int brow8   = l >> 3;                       // row within 8-row chunk
    const int bcol_sw = (((l & 7) ^ (l >> 3)) * 8);   // PRE-SWIZZLED source col (bf16)

    for (int k0 = 0; k0 < K; k0 += 64) {
        if constexpr (AF32) {
            // reg-staged f32 -> bf16, ds_write with swizzled address
            const float* Af = (const float*)Agv;
            #pragma unroll
            for (int pi = 0; pi < 4; ++pi) {
                int idx8 = pi * 256 + t;            // 0..1023
                int row  = idx8 >> 3;               // 0..127
                int cg   = (idx8 & 7) * 8;          // bf16 elems 0..56
                int ga = bm + row; if (ga >= M) ga = M - 1;
                const float* src = Af + (size_t)ga * K + k0 + cg;
                f32x4 u = *reinterpret_cast<const f32x4*>(src);
                f32x4 v = *reinterpret_cast<const f32x4*>(src + 4);
                bf16x8v o;
                o[0] = (short)f2b(u[0]); o[1] = (short)f2b(u[1]);
                o[2] = (short)f2b(u[2]); o[3] = (short)f2b(u[3]);
                o[4] = (short)f2b(v[0]); o[5] = (short)f2b(v[1]);
                o[6] = (short)f2b(v[2]); o[7] = (short)f2b(v[3]);
                *reinterpret_cast<bf16x8v*>(As + row * 64 + (cg ^ ((row & 7) * 8))) = o;
            }
        } else {
            const bf16* Ab = (const bf16*)Agv;
            #pragma unroll
            for (int i = 0; i < 4; ++i) {
                int c = wv * 4 + i;
                int row = c * 8 + brow8;
                int ga = bm + row; if (ga >= M) ga = M - 1;
                gl_lds16(Ab + (size_t)ga * K + k0 + bcol_sw, As + c * 512);
            }
        }
        #pragma unroll
        for (int i = 0; i < 4; ++i) {
            int c = wv * 4 + i;
            int row = c * 8 + brow8;
            gl_lds16(Bt + (size_t)(bn + row) * K + k0 + bcol_sw, Bs + c * 512);
        }
        __syncthreads();

        #pragma unroll
        for (int ks = 0; ks < 2; ++ks) {
            bf16x8v a[4], b[4];
            const int kb = ks * 64 + (l >> 4) * 16;   // byte offset pre-swizzle
            #pragma unroll
            for (int m = 0; m < 4; ++m) {
                int r = wr * 64 + m * 16 + l15;
                a[m] = *reinterpret_cast<const bf16x8v*>(
                           (const char*)As + r * 128 + (kb ^ ((r & 7) << 4)));
            }
            #pragma unroll
            for (int n = 0; n < 4; ++n) {
                int r = wc * 64 + n * 16 + l15;
                b[n] = *reinterpret_cast<const bf16x8v*>(
                           (const char*)Bs + r * 128 + (kb ^ ((r & 7) << 4)));
            }
            #pragma unroll
            for (int m = 0; m < 4; ++m)
                #pragma unroll
                for (int n = 0; n < 4; ++n)
                    acc[m][n] = __builtin_amdgcn_mfma_f32_16x16x32_bf16(a[m], b[n], acc[m][n], 0, 0, 0);
        }
        __syncthreads();
    }

    if (EPI == 3) {
        int oi = bn >> 8;
        bf16* CC = (oi == 0) ? Cg : (oi == 1) ? Cg2 : Cg3;
        const float* bb = (oi == 0) ? bias : (oi == 1) ? bias2 : nullptr;
        int cb = bn & 255;
        float bv[4];
        #pragma unroll
        for (int n = 0; n < 4; ++n)
            bv[n] = bb ? bb[cb + wc * 64 + n * 16 + l15] : 0.f;
        #pragma unroll
        for (int m = 0; m < 4; ++m) {
            #pragma unroll
            for (int i = 0; i < 4; ++i) {
                int row = bm + wr * 64 + m * 16 + (l >> 4) * 4 + i;
                if (row >= M) continue;
                size_t base = (size_t)row * 256 + cb + wc * 64 + l15;
                #pragma unroll
                for (int n = 0; n < 4; ++n)
                    reinterpret_cast<unsigned short*>(CC)[base + n * 16] = f2b(acc[m][n][i] + bv[n]);
            }
        }
    } else if (EPI == 4) {
        float bv[4], bw[4];
        #pragma unroll
        for (int n = 0; n < 4; ++n) {
            int col = bn + wc * 64 + n * 16 + l15;
            bv[n] = bias[col];
            bw[n] = b2w3v[col];
        }
        #pragma unroll
        for (int m = 0; m < 4; ++m) {
            #pragma unroll
            for (int i = 0; i < 4; ++i) {
                int row = bm + wr * 64 + m * 16 + (l >> 4) * 4 + i;
                if (row >= M) continue;
                float d = (float)deg[row];
                size_t base = (size_t)row * Nc + bn + wc * 64 + l15;
                #pragma unroll
                for (int n = 0; n < 4; ++n) {
                    size_t idx = base + (size_t)n * 16;
                    float sv = b2f(reinterpret_cast<const unsigned short*>(Sb)[idx]);
                    float zv = b2f(reinterpret_cast<const unsigned short*>(z0b)[idx]);
                    float v = 0.5f * (d * (sv + bw[n]) + acc[m][n][i]) + 0.5f * zv + bv[n];
                    v = fmaxf(v, 0.f);
                    reinterpret_cast<unsigned short*>(Cg)[idx] = f2b(v);
                }
            }
        }
    } else {
        float bv[4];
        #pragma unroll
        for (int n = 0; n < 4; ++n)
            bv[n] = bias ? bias[bn + wc * 64 + n * 16 + l15] : 0.f;
        #pragma unroll
        for (int m = 0; m < 4; ++m) {
            #pragma unroll
            for (int i = 0; i < 4; ++i) {
                int row = bm + wr * 64 + m * 16 + (l >> 4) * 4 + i;
                if (row >= M) continue;
                size_t base = (size_t)row * Nc + bn + wc * 64 + l15;
                #pragma unroll
                for (int n = 0; n < 4; ++n) {
                    float v = acc[m][n][i] + bv[n];
                    if (EPI == 1) v = fmaxf(v, 0.f);
                    reinterpret_cast<unsigned short*>(Cg)[base + n * 16] = f2b(v);
                }
            }
        }
    }
}

// ---------- gather segment-sum: dst[seg] = sum_{j in seg} src[adj[j]] ----------
__global__ __launch_bounds__(256)
void gather_sum_k(const bf16* __restrict__ src, const int* __restrict__ adj,
                  const int* __restrict__ off, bf16* __restrict__ dst, int nseg)
{
    int seg = blockIdx.x * 4 + (threadIdx.x >> 6);
    if (seg >= nseg) return;
    int lane = threadIdx.x & 63;
    int s0 = off[seg], s1 = off[seg + 1];
    float4 acc = make_float4(0.f, 0.f, 0.f, 0.f);
    int j = s0;
    for (; j + 4 <= s1; j += 4) {
        int r0 = adj[j], r1 = adj[j + 1], r2 = adj[j + 2], r3 = adj[j + 3];
        float4 v0 = load4f(src + (size_t)r0 * HD + lane * 4);
        float4 v1 = load4f(src + (size_t)r1 * HD + lane * 4);
        float4 v2 = load4f(src + (size_t)r2 * HD + lane * 4);
        float4 v3 = load4f(src + (size_t)r3 * HD + lane * 4);
        acc.x += (v0.x + v1.x) + (v2.x + v3.x);
        acc.y += (v0.y + v1.y) + (v2.y + v3.y);
        acc.z += (v0.z + v1.z) + (v2.z + v3.z);
        acc.w += (v0.w + v1.w) + (v2.w + v3.w);
    }
    for (; j < s1; ++j) {
        float4 v = load4f(src + (size_t)adj[j] * HD + lane * 4);
        acc.x += v.x; acc.y += v.y; acc.z += v.z; acc.w += v.w;
    }
    store4(dst + (size_t)seg * HD + lane * 4, acc);
}

// ---------- MFMA classifier: out[M,40] = H[M,256] @ cw2t[48,256]^T + cb2 ----------
__global__ __launch_bounds__(256)
void cls_mfma_k(const bf16* __restrict__ Hm, const bf16* __restrict__ Wt,
                const float* __restrict__ bias, float* __restrict__ out, int M)
{
    const int wv = threadIdx.x >> 6, l = threadIdx.x & 63;
    const int l15 = l & 15;
    const int r0 = blockIdx.x * 64 + wv * 16;
    f32x4 acc[3];
    #pragma unroll
    for (int n = 0; n < 3; ++n) acc[n] = (f32x4){0.f, 0.f, 0.f, 0.f};

    int arow = r0 + l15; if (arow >= M) arow = M - 1;
    const int ko = (l >> 4) * 8;
    for (int kk = 0; kk < HD; kk += 32) {
        bf16x8v a = *reinterpret_cast<const bf16x8v*>(Hm + (size_t)arow * HD + kk + ko);
        #pragma unroll
        for (int n = 0; n < 3; ++n) {
            bf16x8v b = *reinterpret_cast<const bf16x8v*>(Wt + (size_t)(n * 16 + l15) * HD + kk + ko);
            acc[n] = __builtin_amdgcn_mfma_f32_16x16x32_bf16(a, b, acc[n], 0, 0, 0);
        }
    }
    #pragma unroll
    for (int n = 0; n < 3; ++n) {
        int col = n * 16 + l15;
        if (col >= NCLS) continue;
        float bv = bias[col];
        #pragma unroll
        for (int i = 0; i < 4; ++i) {
            int row = r0 + (l >> 4) * 4 + i;
            if (row < M) out[(size_t)row * NCLS + col] = acc[n][i] + bv;
        }
    }
}

// XCD-grouped 1-D grid size for an (M, Nc) GEMM
static inline int xcd_grid(int M, int Nc)
{
    int nbm = (M + 127) >> 7;
    int nbn = Nc >> 7;
    return nbn * (((nbm + 7) / 8) * 8);
}

extern "C" void kernel_launch(void* const* d_in, const int* in_sizes, int n_in,
                              void* d_out, int out_size, void* d_ws, size_t ws_size,
                              hipStream_t stream)
{
    const float* x_in   = (const float*)d_in[0];
    const int*   vertex = (const int*)d_in[1];
    const int*   edges  = (const int*)d_in[2];
    const float* lin_w  = (const float*)d_in[3];
    const float* lin_b  = (const float*)d_in[4];
    const float* w1     = (const float*)d_in[5];
    const float* b1     = (const float*)d_in[6];
    const float* w2     = (const float*)d_in[7];
    const float* b2     = (const float*)d_in[8];
    const float* w3     = (const float*)d_in[9];
    const float* b3     = (const float*)d_in[10];
    const float* cw1    = (const float*)d_in[11];
    const float* cb1    = (const float*)d_in[12];
    const float* cw2    = (const float*)d_in[13];
    const float* cb2    = (const float*)d_in[14];
    float* out = (float*)d_out;
    (void)in_sizes; (void)n_in; (void)out_size; (void)ws_size;

    char* ws = (char*)d_ws;
    const size_t nvhd = (size_t)NV * HD, nehd = (size_t)NE * HD;
    size_t off = 0;
    auto alloc = [&](size_t bytes) { char* p = ws + off; off += (bytes + 255) & ~(size_t)255; return p; };
    bf16* x0 = (bf16*)alloc(nvhd * 2);          // restart anchor
    bf16* xA = (bf16*)alloc(nvhd * 2);          // layer output
    bf16* E1 = (bf16*)alloc(nehd * 2);          // T1 -> ge -> cls hidden
    bf16* E2 = (bf16*)alloc(nehd * 2);          // xe
    bf16* S  = (bf16*)alloc(nvhd * 2);          // cur @ W23a
    bf16* z0 = (bf16*)alloc(nvhd * 2);          // x0 @ w3
    // [w1t ; W23at ; w3t] MUST be contiguous (triple-GEMM B operand)
    unsigned short* w1t    = (unsigned short*)alloc(3 * 256 * 256 * 2);
    unsigned short* W23at  = w1t + 65536;
    unsigned short* w3t    = w1t + 131072;
    unsigned short* W23bt  = (unsigned short*)alloc(256 * 256 * 2);
    unsigned short* w2ab   = (unsigned short*)alloc(512 * 256 * 2);  // [w2a_nb ; w2b_nb]
    unsigned short* w2a_nb = w2ab;
    unsigned short* w2b_nb = w2ab + 256 * 256;
    unsigned short* lin_wt = (unsigned short*)alloc(256 * 512 * 2);
    unsigned short* cw1t   = (unsigned short*)alloc(256 * 256 * 2);
    unsigned short* cw2t   = (unsigned short*)alloc(48 * 256 * 2);
    float* b2w3 = (float*)alloc(256 * 4);
    int* cnt_e = (int*)alloc(NE * 4);            // edge degree; cnt_v MUST follow (single fill)
    int* cnt_v = (int*)alloc(NV * 4);            // vertex degree (EPI4)
    int* off_e = (int*)alloc((NE + 1) * 4);
    int* off_v = (int*)alloc((NV + 1) * 4);
    int* cur_e = (int*)alloc(NE * 4);
    int* cur_v = (int*)alloc(NV * 4);
    int* part_e = (int*)alloc(256 * 4);
    int* part_v = (int*)alloc(256 * 4);
    int* adj_e = (int*)alloc((size_t)NNZC * 4);
    int* adj_v = (int*)alloc((size_t)NNZC * 4);

    dim3 blk(256);

    // ---- CSR build (6 launches) ----
    fill0_k<<<128, blk, 0, stream>>>((unsigned int*)cnt_e, NE + NV);
    hist_k<<<(NNZC + 255) / 256, blk, 0, stream>>>(vertex, edges, cnt_v, cnt_e, NNZC);
    scan_part2_k<<<dim3(NCH_E, 2), blk, 0, stream>>>(cnt_e, off_e, part_e, cnt_v, off_v, part_v);
    scan_top2_k<<<2, blk, 0, stream>>>(part_e, off_e + NE, part_v, off_v + NV);
    scan_addcur2_k<<<dim3((NE + 255) / 256, 2), blk, 0, stream>>>(off_e, part_e, cur_e,
                                                                  off_v, part_v, cur_v);
    csr_fill_k<<<(NNZC + 255) / 256, blk, 0, stream>>>(vertex, edges, cur_e, cur_v, adj_e, adj_v, NNZC);

    // ---- weight prep + composition (2 launches) ----
    prep_w_k<<<1841, blk, 0, stream>>>(lin_w, w1, w2, w3, cw1, cw2, b2,
                                       lin_wt, w1t, w2a_nb, w2b_nb, w3t, cw1t, cw2t, b2w3);
    // [W23at | W23bt] = w3t @ [w2a;w2b]^T  (EPI3 split-store)
    mgemm_k<3, false><<<xcd_grid(256, 512), blk, 0, stream>>>((const bf16*)w3t, (const bf16*)w2ab,
        nullptr, nullptr, nullptr, nullptr, nullptr, nullptr,
        (bf16*)W23at, (bf16*)W23bt, nullptr, 256, 256, 512);

    // ---- input projection: x0 = relu(x_in(f32) @ lin_w + lin_b), reg-staged A ----
    mgemm_k<1, true><<<xcd_grid(NV, 256), blk, 0, stream>>>(x_in, (const bf16*)lin_wt,
        lin_b, nullptr, nullptr, nullptr, nullptr, nullptr,
        x0, nullptr, nullptr, NV, FINC, HD);

    const bf16* cur = x0;
    for (int layer = 0; layer < 2; ++layer) {
        if (layer == 0) {
            // [E1(T1) | S | z0] = x0 @ [w1t ; W23at ; w3t]   (triple GEMM)
            mgemm_k<3, false><<<xcd_grid(NV, 768), blk, 0, stream>>>(cur, (const bf16*)w1t,
                b1, nullptr, nullptr, nullptr, nullptr, nullptr,
                E1, S, z0, NV, HD, 768);
        } else {
            // [E1(T1) | S] = cur @ [w1t ; W23at]   (dual GEMM)
            mgemm_k<3, false><<<xcd_grid(NV, 512), blk, 0, stream>>>(cur, (const bf16*)w1t,
                b1, nullptr, nullptr, nullptr, nullptr, nullptr,
                E1, S, nullptr, NV, HD, 512);
        }
        // E2(xe) = segment_sum(T1[vertex], edges)
        gather_sum_k<<<(NE + 3) / 4, blk, 0, stream>>>(E1, adj_e, off_e, E2, NE);
        // E1(ge) = segment_sum(xe[edges], vertex)
        gather_sum_k<<<(NV + 3) / 4, blk, 0, stream>>>(E2, adj_v, off_v, E1, NV);
        // xA = relu(0.5*(deg*(S + b2w3) + ge@W23b) + 0.5*z0 + b3)
        mgemm_k<4, false><<<xcd_grid(NV, 256), blk, 0, stream>>>(E1, (const bf16*)W23bt,
            b3, nullptr, cnt_v, S, z0, b2w3,
            xA, nullptr, nullptr, NV, HD, HD);
        cur = xA;
    }

    // ---- classifier ----
    mgemm_k<1, false><<<xcd_grid(NV, 256), blk, 0, stream>>>(xA, (const bf16*)cw1t,
        cb1, nullptr, nullptr, nullptr, nullptr, nullptr,
        E1, nullptr, nullptr, NV, HD, HD);
    cls_mfma_k<<<(NV + 63) / 64, blk, 0, stream>>>(E1, (const bf16*)cw2t, cb2, out, NV);
}